// Round 10
// baseline (126.998 us; speedup 1.0000x reference)
//
#include <hip/hip_runtime.h>

#define N_ROWS 32768
#define DIM    256
#define KCODES 2048
#define CSCALE 4096.0f
#define RPB    32          // rows per block

typedef __attribute__((ext_vector_type(16))) float f32x16;
typedef __attribute__((ext_vector_type(4)))  unsigned int u32x4;

union frag16 { u32x4 v; long l[2]; };

// s_waitcnt immediates (gfx9/CDNA: vmcnt[3:0]+[15:14], expcnt[6:4], lgkmcnt[11:8])
#define WAIT_LGKM0 0xC07F   // lgkmcnt(0)
#define WAIT_VM4   0x0F74   // vmcnt(4)
#define WAIT_VM0   0x0F70   // vmcnt(0)

__device__ __forceinline__ void gl16(const void* g, void* l) {
    __builtin_amdgcn_global_load_lds(
        (const __attribute__((address_space(1))) unsigned int*)g,
        (__attribute__((address_space(3))) unsigned int*)l, 16, 0, 0);
}

// pack 16 fp32 -> 16 fp8 e4m3 (4 dwords)
__device__ __forceinline__ uint4 pack16(const float* s) {
    int a = __builtin_amdgcn_cvt_pk_fp8_f32(s[0],  s[1],  0, false);
    a     = __builtin_amdgcn_cvt_pk_fp8_f32(s[2],  s[3],  a, true);
    int b = __builtin_amdgcn_cvt_pk_fp8_f32(s[4],  s[5],  0, false);
    b     = __builtin_amdgcn_cvt_pk_fp8_f32(s[6],  s[7],  b, true);
    int c = __builtin_amdgcn_cvt_pk_fp8_f32(s[8],  s[9],  0, false);
    c     = __builtin_amdgcn_cvt_pk_fp8_f32(s[10], s[11], c, true);
    int d = __builtin_amdgcn_cvt_pk_fp8_f32(s[12], s[13], 0, false);
    d     = __builtin_amdgcn_cvt_pk_fp8_f32(s[14], s[15], d, true);
    uint4 o; o.x = a; o.y = b; o.z = c; o.w = d;
    return o;
}

// Piece layout (per 64B k-chunk): piece d (=h*2+q, 16B) holds the two 8B MFMA
// fragments (ks=2q,2q+1) for k-half h:
//   bytes [0,8)  = k = q*32      + h*8 + [0,8)
//   bytes [8,16) = k = q*32 + 16 + h*8 + [0,8)

// ---------------- prologue: cb -> fp8 (x4096) in piece layout + halfcn ----------
__global__ void prep_cb(const float* __restrict__ cb, unsigned int* __restrict__ cbf8,
                        float* __restrict__ halfcn, float* __restrict__ loss) {
    const int t    = threadIdx.x;            // 256 thr = 4 codes x 64 dword slots
    const int code = blockIdx.x * 4 + (t >> 6);
    const int s    = t & 63;                 // output dword slot
    if (blockIdx.x == 0 && t == 0) *loss = 0.0f;
    const int kc = s >> 4, d = (s >> 2) & 3, b4 = (s & 3) * 4;
    const int h = d >> 1, q = d & 1;
    const int k0 = kc * 64 + q * 32 + (b4 >> 3) * 16 + h * 8 + (b4 & 7);
    float4 v = *(const float4*)&cb[(size_t)code * DIM + k0];
    int pk = __builtin_amdgcn_cvt_pk_fp8_f32(v.x * CSCALE, v.y * CSCALE, 0, false);
    pk     = __builtin_amdgcn_cvt_pk_fp8_f32(v.z * CSCALE, v.w * CSCALE, pk, true);
    cbf8[(size_t)code * 64 + s] = (unsigned int)pk;
    float ssum = v.x * v.x + v.y * v.y + v.z * v.z + v.w * v.w;
    #pragma unroll
    for (int o = 32; o > 0; o >>= 1) ssum += __shfl_down(ssum, o, 64);
    if (s == 0) halfcn[code] = 0.5f * CSCALE * ssum;
}

// ---------------- fused: 32 rows x 2048 codes, A-in-registers -------------------
// grid = 1024 blocks = 4 blocks/CU resident (launch_bounds(256,4), LDS 32.8KB).
// A fragments (this lane's row l32, all 4 k-chunks) live in 32 VGPRs; only B
// flows through a wave-private 2-ring in LDS (waitcnt-paced, barrier-free loop).
__global__ __launch_bounds__(256, 4) void vq_fused(
        const float* __restrict__ x, const float* __restrict__ cb,
        const char* __restrict__ cbf8, const float* __restrict__ halfcn,
        float* __restrict__ out, float* __restrict__ loss) {
    __shared__ char mem[32768];   // overlay: A-stage (8KB) -> B-ring [2][4][4KB] -> reductions

    const int t    = threadIdx.x;
    const int lane = t & 63;
    const int w    = t >> 6;
    const int l32  = lane & 31;
    const int h    = lane >> 5;
    const int row0 = blockIdx.x * RPB;

    // ---- stage A: fp32 x -> fp8 pieces into mem[kc*2048 + r*64 + p*16] ----
    {
        const int r   = t >> 3;               // row 0..31
        const int sub = t & 7;
        const int kc  = sub >> 1;
        const int pb  = (sub & 1) * 2;        // pieces {pb, pb+1}
        const int key = (r >> 1) & 3;
        const float* src = x + (size_t)(row0 + r) * DIM + kc * 64;
        float buf[16];
        #pragma unroll
        for (int pi = 0; pi < 2; pi++) {
            const int p = pb + pi;
            const int d = p ^ key, hh = d >> 1, qq = d & 1;
            #pragma unroll
            for (int j = 0; j < 4; j++) *(float4*)(buf + j * 4) =
                *(const float4*)(src + qq * 32 + (j >> 1) * 16 + hh * 8 + (j & 1) * 4);
            *(uint4*)(mem + kc * 2048 + r * 64 + p * 16) = pack16(buf);
        }
    }
    __syncthreads();

    // ---- A fragments -> registers (row = l32, all 4 k-chunks) ----
    const int key = (l32 >> 1) & 3;
    const int p0  = (h * 2 + 0) ^ key;
    const int p1  = (h * 2 + 1) ^ key;
    frag16 afr[4][2];
    #pragma unroll
    for (int kc = 0; kc < 4; kc++) {
        afr[kc][0].v = *(const u32x4*)(mem + kc * 2048 + l32 * 64 + p0 * 16);
        afr[kc][1].v = *(const u32x4*)(mem + kc * 2048 + l32 * 64 + p1 * 16);
    }
    __syncthreads();   // all waves done reading A; mem now owned by the B-ring

    // ---- wave-private B staging: 4KB (wave's 64 codes x 64B) per step ----
    const int lsub = lane >> 2;
    const int lpos = lane & 3;
    auto stageB = [&](int i) {
        const int pass = i >> 2, kc = i & 3;
        char* dst = mem + (i & 1) * 16384 + w * 4096;
        #pragma unroll
        for (int r_ = 0; r_ < 4; r_++) {
            const int lc = r_ * 16 + lsub;
            const int g  = lpos ^ ((lc >> 1) & 3);
            const char* src = cbf8 + (size_t)(pass * 256 + w * 64 + lc) * 256
                              + kc * 64 + g * 16;
            gl16(src, dst + r_ * 1024);
        }
    };

    float mp[16];
    #pragma unroll
    for (int r = 0; r < 16; r++) mp[r] = -3.0e38f;

    float hc0 = halfcn[w * 64 + l32];
    float hc1 = halfcn[w * 64 + 32 + l32];

    stageB(0);
    for (int pass = 0; pass < 8; ++pass) {
        f32x16 acc[2];
        #pragma unroll
        for (int r = 0; r < 16; r++) { acc[0][r] = -hc0; acc[1][r] = -hc1; }
        float hc0n = 0.0f, hc1n = 0.0f;
        if (pass < 7) {
            hc0n = halfcn[(pass + 1) * 256 + w * 64 + l32];
            hc1n = halfcn[(pass + 1) * 256 + w * 64 + 32 + l32];
        }

        #pragma unroll
        for (int kc = 0; kc < 4; ++kc) {
            const int i = pass * 4 + kc;
            // prior step's B frag reads have landed -> safe to overwrite its buffer
            __builtin_amdgcn_s_waitcnt(WAIT_LGKM0);
            if (i + 1 < 32) {
                stageB(i + 1);
                __builtin_amdgcn_s_waitcnt(WAIT_VM4);   // stage(i) complete; i+1 in flight
            } else {
                __builtin_amdgcn_s_waitcnt(WAIT_VM0);
            }

            const char* bb = mem + (i & 1) * 16384 + w * 4096;
            frag16 bf[2][2];
            #pragma unroll
            for (int ct = 0; ct < 2; ct++) {
                const int cbase = (ct * 32 + l32) * 64;
                bf[ct][0].v = *(const u32x4*)(bb + cbase + p0 * 16);
                bf[ct][1].v = *(const u32x4*)(bb + cbase + p1 * 16);
            }
            #pragma unroll
            for (int q = 0; q < 2; q++)
                #pragma unroll
                for (int hf = 0; hf < 2; hf++)
                    #pragma unroll
                    for (int ct = 0; ct < 2; ct++)
                        acc[ct] = __builtin_amdgcn_mfma_f32_32x32x16_fp8_fp8(
                            afr[kc][q].l[hf], bf[ct][q].l[hf], acc[ct], 0, 0, 0);
        }

        // fold pass into running max (11-bit code id in low mantissa bits)
        #pragma unroll
        for (int ct = 0; ct < 2; ct++) {
            const unsigned code = (unsigned)(pass * 256 + w * 64 + ct * 32 + l32);
            #pragma unroll
            for (int r = 0; r < 16; r++) {
                unsigned u = (__float_as_uint(acc[ct][r]) & 0xFFFFF800u) | code;
                mp[r] = fmaxf(mp[r], __uint_as_float(u));
            }
        }
        hc0 = hc0n; hc1 = hc1n;
    }

    // ---- cross-lane argmax over the 32 lanes sharing each output row ----
    #pragma unroll
    for (int m = 1; m <= 16; m <<= 1)
        #pragma unroll
        for (int r = 0; r < 16; r++)
            mp[r] = fmaxf(mp[r], __shfl_xor(mp[r], m, 64));

    __syncthreads();                       // K-loop LDS traffic done; reuse mem
    float* red  = (float*)mem;             // [32][4]
    int*   idxs = (int*)(mem + 1024);      // [32]
    float* lred = (float*)(mem + 2048);    // [4]

    if (l32 == 0) {
        #pragma unroll
        for (int r = 0; r < 16; r++) {
            const int row = (r & 3) + 8 * (r >> 2) + 4 * h;
            red[row * 4 + w] = mp[r];
        }
    }
    __syncthreads();
    if (t < RPB) {
        float b0 = fmaxf(fmaxf(red[t * 4 + 0], red[t * 4 + 1]),
                         fmaxf(red[t * 4 + 2], red[t * 4 + 3]));
        idxs[t] = (int)(__float_as_uint(b0) & 2047u);
    }
    __syncthreads();

    // ---- fused gather (fp32 codebook) + loss partial ----
    float lsum = 0.0f;
    #pragma unroll 4
    for (int r = 0; r < RPB; r++) {
        const int code = idxs[r];
        const float c  = cb[(size_t)code * DIM + t];
        const float xv = x[(size_t)(row0 + r) * DIM + t];
        out[(size_t)(row0 + r) * DIM + t] = c;
        const float d = xv - c;
        lsum += d * d;
    }
    #pragma unroll
    for (int o = 32; o > 0; o >>= 1) lsum += __shfl_down(lsum, o, 64);
    if (lane == 0) lred[w] = lsum;
    __syncthreads();
    if (t == 0) {
        const float scale = 1.25f / (float)((size_t)N_ROWS * DIM);  // (beta+1)/(N*D)
        atomicAdd(loss, (lred[0] + lred[1] + lred[2] + lred[3]) * scale);
    }
}

extern "C" void kernel_launch(void* const* d_in, const int* in_sizes, int n_in,
                              void* d_out, int out_size, void* d_ws, size_t ws_size,
                              hipStream_t stream) {
    const float* x  = (const float*)d_in[0];
    const float* cb = (const float*)d_in[1];
    float* out  = (float*)d_out;
    float* loss = out + (size_t)N_ROWS * DIM;

    char* ws = (char*)d_ws;
    unsigned int* cbf8 = (unsigned int*)ws;                        // 512 KB
    float* halfcn = (float*)(ws + (size_t)KCODES * 256);           // 8 KB

    prep_cb<<<KCODES / 4, 256, 0, stream>>>(cb, cbf8, halfcn, loss);
    vq_fused<<<N_ROWS / RPB, 256, 0, stream>>>(x, cb, (const char*)cbf8, halfcn, out, loss);
}